// Round 8
// baseline (500.051 us; speedup 1.0000x reference)
//
#include <hip/hip_runtime.h>
#include <hip/hip_bf16.h>
#include <math.h>

// ---------------- problem constants ----------------
#define BATCH 4
#define TLEN  2048
#define DIM   1024
#define NROWS (BATCH*TLEN)      // 8192
#define HDIM  (4*DIM)           // 4096

typedef __hip_bfloat16 bf16;
typedef __attribute__((ext_vector_type(8))) short   shortx8;   // 8 bf16 = 4 VGPR
typedef __attribute__((ext_vector_type(4))) float   floatx4;

__device__ __forceinline__ unsigned short f2bf(float f) {
    bf16 h = __float2bfloat16(f);
    return __builtin_bit_cast(unsigned short, h);
}

__device__ __forceinline__ void async16(const void* g, void* l) {
    // global -> LDS direct DMA, 16B/lane. LDS dest is wave-uniform base + lane*16.
    __builtin_amdgcn_global_load_lds((const __attribute__((address_space(1))) void*)g,
                                     (__attribute__((address_space(3))) void*)l, 16, 0, 0);
}

enum { EP_NONE=0, EP_SIGMOID=1, EP_ADD=2, EP_SQRELU=3, EP_FINAL=4 };

typedef const __attribute__((address_space(3))) char* lds3_t;

// ============================================================================
// GEMM v6 = R5's 128x256 / 512-thr core with the ring deepened 5 -> 6
// regions (144 KB LDS) and stage-ahead 4 -> 5.
// R6 post-mortem: staging service rate tracks BYTES IN FLIGHT (MLP):
//   32KB in flight (R6 big core)  ->  ~8 B/cy/CU
//   48KB in flight (R5)           -> 14.3 B/cy/CU
//   deeper pipelines (m97/m201)   -> 19-22 B/cy/CU
// and every kernel so far ran 1 block/CU (120KB LDS), so there is no
// cross-block overlap to hide the vmcnt stall: phase time == slice service
// time.  This version keeps 72KB (3 slices) in flight with 3-phase cover.
//
// LEDGER (3 loads/stage, read-ahead 1, stage-ahead 5):
//   prologue: stage slices 0..4 (15 loads); vmcnt(9) drains slices 0,1
//             (needed by pre-loop ldfrag(0) and phase 0's ldfrag(1)).
//   phase q:  stage(q+5) -> region (q+5)%6   [prev occupant slice q-1:
//               its ds_reads drained by phase q-1's lgkmcnt(8), collective
//               via phase q-1's barrier -> safe]
//             ldfrag slice q+1               [drained by phase q-1's vmcnt(9)]
//             lgkmcnt(8)                     [drains slice q's 8 reads only]
//             sched_barrier; 16 MFMA slice q
//             vmcnt(9): outstanding {q+2..q+5}=12 -> drains slice q+2
//               (staged at phase q-3: 3-phase cover), leaves 9 = 72KB.
//             s_barrier (collective completion of q+2) ; sched_barrier.
//   main loop phases 0..P-7 (even count for P=32,128), peeled phase P-6
//   (stages slice P-1), tail phases P-5..P-1 with vmcnt 6/3/0 and lgkm 8/0.
//   Barrier count uniform across waves.  P = K/32 >= 7 (32 or 128 here).
// ============================================================================
#define G_REGB   24576       // region bytes (A 8KB + B 16KB)
#define G_ABYTES 8192        // A sub-region bytes
#define G_NSH    (6*12288)   // 6 regions of 12288 shorts = 144 KB

__device__ __forceinline__ void gemm_core(
    const bf16* __restrict__ A, const bf16* __restrict__ Bt, const int K,
    const size_t m0, const size_t n0, short* lds, floatx4 (&acc)[4][4])
{
    const int tid = threadIdx.x;
    char* ldsc = (char*)lds;

    // ---- staging: pre-swizzled per-thread global sources, linear LDS dest.
    // A slot s = tid (512 slots): row = s>>2, kgroup = (s&3) ^ ((row>>1)&3)
    const int rA = tid >> 2;
    const int kA = ((tid & 3) ^ ((rA >> 1) & 3)) << 3;
    const bf16* pA  = A  + (size_t)(m0 + rA) * K + kA;
    const int s1  = 512 + tid;
    const int rB1 = s1 >> 2;
    const int kB1 = ((s1 & 3) ^ ((rB1 >> 1) & 3)) << 3;
    const bf16* pB0 = Bt + (size_t)(n0 + rA)  * K + kA;   // slot tid: same math as A
    const bf16* pB1 = Bt + (size_t)(n0 + rB1) * K + kB1;
    char* dA  = ldsc + tid * 16;
    char* dB0 = ldsc + G_ABYTES + tid * 16;
    char* dB1 = ldsc + G_ABYTES + 8192 + tid * 16;

    // ---- MFMA fragment LDS byte offsets (swizzle-matched)
    const int lane = tid & 63;
    const int wave = tid >> 6;
    const int wm = (wave >> 2) * 64;
    const int wn = (wave & 3) * 64;
    const int lr = lane & 15, kq = lane >> 4;
    int offA[4], offB[4];
    #pragma unroll
    for (int i = 0; i < 4; ++i) {
        const int ra = wm + i*16 + lr;
        offA[i] = ra*64 + ((kq ^ ((ra>>1)&3)) << 4);
        const int rb = wn + i*16 + lr;
        offB[i] = G_ABYTES + rb*64 + ((kq ^ ((rb>>1)&3)) << 4);
    }

    const int P = K >> 5;        // 32 (K=1024) / 128 (K=4096)

    auto stage = [&](int sl, int reg) {
        const int rB = reg * G_REGB;
        const int ko = sl << 5;
        async16(pA  + ko, dA  + rB);
        async16(pB0 + ko, dB0 + rB);
        async16(pB1 + ko, dB1 + rB);
    };
    auto ldfrag = [&](int reg, shortx8 (&af)[4], shortx8 (&bf_)[4]) {
        const char* rb = ldsc + (size_t)(reg * G_REGB);
        #pragma unroll
        for (int i = 0; i < 4; ++i) {
            lds3_t p = (lds3_t)(rb + offA[i]);
            asm volatile("ds_read_b128 %0, %1" : "=v"(af[i]) : "v"(p));
        }
        #pragma unroll
        for (int i = 0; i < 4; ++i) {
            lds3_t p = (lds3_t)(rb + offB[i]);
            asm volatile("ds_read_b128 %0, %1" : "=v"(bf_[i]) : "v"(p));
        }
    };
    auto domfma = [&](const shortx8 (&af)[4], const shortx8 (&bf_)[4]) {
        __builtin_amdgcn_s_setprio(1);
        #pragma unroll
        for (int mi = 0; mi < 4; ++mi)
            #pragma unroll
            for (int ni = 0; ni < 4; ++ni)
                acc[mi][ni] = __builtin_amdgcn_mfma_f32_16x16x32_bf16(
                                  af[mi], bf_[ni], acc[mi][ni], 0, 0, 0);
        __builtin_amdgcn_s_setprio(0);
    };

    // prologue: fill 5 regions (15 loads); drain slices 0,1 -> vmcnt(9)
    stage(0,0); stage(1,1); stage(2,2); stage(3,3); stage(4,4);
    asm volatile("s_waitcnt vmcnt(9)" ::: "memory");
    __builtin_amdgcn_s_barrier();
    __builtin_amdgcn_sched_barrier(0);

    shortx8 fa0[4], fb0[4], fa1[4], fb1[4];
    ldfrag(0, fa0, fb0);                 // slice 0 (8 lgkm in flight)

    // main loop, 2 phases/iter over phases 0..P-7 (count P-6: even for 32,128)
    // invariant at top: fa0/fb0 = slice q frags (reads in flight), cur = q%6.
    int cur = 0;
    for (int q = 0; q < P - 6; q += 2) {
        {   // even phase q: stage q+5, read q+1, mfma q
            const int st = (cur == 0) ? 5 : cur - 1;     // (q+5)%6
            stage(q + 5, st);
            const int rd = (cur == 5) ? 0 : cur + 1;     // (q+1)%6
            ldfrag(rd, fa1, fb1);
            asm volatile("s_waitcnt lgkmcnt(8)" ::: "memory");
            __builtin_amdgcn_sched_barrier(0);
            domfma(fa0, fb0);
            asm volatile("s_waitcnt vmcnt(9)" ::: "memory");
            __builtin_amdgcn_s_barrier();
            __builtin_amdgcn_sched_barrier(0);
            cur = rd;
        }
        {   // odd phase q+1: stage q+6, read q+2, mfma q+1
            const int st = (cur == 0) ? 5 : cur - 1;     // (q+6)%6
            stage(q + 6, st);
            const int rd = (cur == 5) ? 0 : cur + 1;     // (q+2)%6
            ldfrag(rd, fa0, fb0);
            asm volatile("s_waitcnt lgkmcnt(8)" ::: "memory");
            __builtin_amdgcn_sched_barrier(0);
            domfma(fa1, fb1);
            asm volatile("s_waitcnt vmcnt(9)" ::: "memory");
            __builtin_amdgcn_s_barrier();
            __builtin_amdgcn_sched_barrier(0);
            cur = rd;
        }
    }

    // peeled phase P-6 (even parity): stage P-1, read P-5, mfma P-6
    {
        const int st = (cur == 0) ? 5 : cur - 1;
        stage(P - 1, st);
        const int rd = (cur == 5) ? 0 : cur + 1;
        ldfrag(rd, fa1, fb1);
        asm volatile("s_waitcnt lgkmcnt(8)" ::: "memory");
        __builtin_amdgcn_sched_barrier(0);
        domfma(fa0, fb0);
        asm volatile("s_waitcnt vmcnt(9)" ::: "memory");   // drains slice P-4
        __builtin_amdgcn_s_barrier();
        __builtin_amdgcn_sched_barrier(0);
        cur = rd;
    }
    // tail: phases P-5..P-1, no staging; vmcnt 6 / 3 / 0
    {
        // P-5 (odd): read P-4, mfma P-5; drain P-3
        int rd = (cur == 5) ? 0 : cur + 1;
        ldfrag(rd, fa0, fb0);
        asm volatile("s_waitcnt lgkmcnt(8)" ::: "memory");
        __builtin_amdgcn_sched_barrier(0);
        domfma(fa1, fb1);
        asm volatile("s_waitcnt vmcnt(6)" ::: "memory");
        __builtin_amdgcn_s_barrier();
        __builtin_amdgcn_sched_barrier(0);
        cur = rd;
        // P-4 (even): read P-3, mfma P-4; drain P-2
        rd = (cur == 5) ? 0 : cur + 1;
        ldfrag(rd, fa1, fb1);
        asm volatile("s_waitcnt lgkmcnt(8)" ::: "memory");
        __builtin_amdgcn_sched_barrier(0);
        domfma(fa0, fb0);
        asm volatile("s_waitcnt vmcnt(3)" ::: "memory");
        __builtin_amdgcn_s_barrier();
        __builtin_amdgcn_sched_barrier(0);
        cur = rd;
        // P-3 (odd): read P-2, mfma P-3; drain P-1
        rd = (cur == 5) ? 0 : cur + 1;
        ldfrag(rd, fa0, fb0);
        asm volatile("s_waitcnt lgkmcnt(8)" ::: "memory");
        __builtin_amdgcn_sched_barrier(0);
        domfma(fa1, fb1);
        asm volatile("s_waitcnt vmcnt(0)" ::: "memory");
        __builtin_amdgcn_s_barrier();
        __builtin_amdgcn_sched_barrier(0);
        cur = rd;
        // P-2 (even): read P-1, mfma P-2 (no barrier: no restage follows)
        rd = (cur == 5) ? 0 : cur + 1;
        ldfrag(rd, fa1, fb1);
        asm volatile("s_waitcnt lgkmcnt(8)" ::: "memory");
        __builtin_amdgcn_sched_barrier(0);
        domfma(fa0, fb0);
        // P-1: mfma P-1
        asm volatile("s_waitcnt lgkmcnt(0)" ::: "memory");
        __builtin_amdgcn_sched_barrier(0);
        domfma(fa1, fb1);
    }
}

// epilogue: C/D layout col=lane&15, row=(lane>>4)*4+reg (verified layout)
template<int MODE, typename OutT>
__device__ __forceinline__ void epilogue(
    floatx4 (&acc)[4][4], OutT* __restrict__ C,
    const float* __restrict__ addv, const bf16* __restrict__ mulv,
    const size_t m0, const size_t n0, const int N)
{
    const int tid = threadIdx.x;
    const int lane = tid & 63, wave = tid >> 6;
    const size_t r0 = m0 + (size_t)(wave >> 2) * 64 + ((lane >> 4) << 2);
    const size_t c0 = n0 + (size_t)(wave & 3) * 64 + (lane & 15);
    #pragma unroll
    for (int mi = 0; mi < 4; ++mi)
      #pragma unroll
      for (int ni = 0; ni < 4; ++ni)
        #pragma unroll
        for (int r = 0; r < 4; ++r) {
            const size_t off = (r0 + mi*16 + r) * N + c0 + ni*16;
            float v = acc[mi][ni][r];
            if (MODE == EP_SIGMOID)      v = 1.0f / (1.0f + __expf(-v));
            else if (MODE == EP_ADD)     v = addv[off] + v;
            else if (MODE == EP_SQRELU)  { float t = fmaxf(v, 0.0f); v = t * t; }
            else if (MODE == EP_FINAL)   v = addv[off] + __bfloat162float(mulv[off]) * v;
            if (sizeof(OutT) == 2) *(unsigned short*)(C + off) = f2bf(v);
            else                   *(float*)(C + off) = v;
        }
}

template<int MODE, typename OutT>
__global__ __launch_bounds__(512, 2)
void gemm256(const bf16* __restrict__ A, const bf16* __restrict__ Bt,
             OutT* __restrict__ C,
             const float* __restrict__ addv, const bf16* __restrict__ mulv,
             int N, int K)
{
    __shared__ __align__(16) short lds[G_NSH];
    const int nwg  = gridDim.x * gridDim.y;
    const int orig = blockIdx.y * gridDim.x + blockIdx.x;
    const int wg   = (orig & 7) * (nwg >> 3) + (orig >> 3);   // nwg % 8 == 0
    const int bx   = wg % gridDim.x;
    const int by   = wg / gridDim.x;
    const size_t m0 = (size_t)bx * 128;
    const size_t n0 = (size_t)by * 256;
    floatx4 acc[4][4] = {};
    gemm_core(A, Bt, K, m0, n0, lds, acc);
    epilogue<MODE, OutT>(acc, C, addv, mulv, m0, n0, N);
}

// ---------------------------------------------------------------------------
// Multi-GEMM: k/v/r (same M=8192, K=1024, N=1024, bf16 out) in ONE dispatch.
// grid = (64, 12): 4 col tiles per descriptor.
// ---------------------------------------------------------------------------
struct GDesc { const bf16* A; const bf16* Bt; bf16* C; int mode; };
struct GArgs { GDesc d[3]; };

__global__ __launch_bounds__(512, 2)
void gemm256_multi(GArgs args)
{
    __shared__ __align__(16) short lds[G_NSH];
    const int nwg  = gridDim.x * gridDim.y;
    const int orig = blockIdx.y * gridDim.x + blockIdx.x;
    const int wg   = (orig & 7) * (nwg >> 3) + (orig >> 3);
    const int bx   = wg % gridDim.x;
    const int byg  = wg / gridDim.x;         // 0..11
    const int di   = byg >> 2;
    const int by   = byg & 3;
    const GDesc d  = args.d[di];
    const size_t m0 = (size_t)bx * 128;
    const size_t n0 = (size_t)by * 256;
    floatx4 acc[4][4] = {};
    gemm_core(d.A, d.Bt, DIM, m0, n0, lds, acc);

    const int tid = threadIdx.x;
    const int lane = tid & 63, wave = tid >> 6;
    const size_t r0 = m0 + (size_t)(wave >> 2) * 64 + ((lane >> 4) << 2);
    const size_t c0 = n0 + (size_t)(wave & 3) * 64 + (lane & 15);
    const bool sig = (d.mode == EP_SIGMOID);
    #pragma unroll
    for (int mi = 0; mi < 4; ++mi)
      #pragma unroll
      for (int ni = 0; ni < 4; ++ni)
        #pragma unroll
        for (int r = 0; r < 4; ++r) {
            const size_t off = (r0 + mi*16 + r) * DIM + c0 + ni*16;
            float v = acc[mi][ni][r];
            if (sig) v = 1.0f / (1.0f + __expf(-v));
            *(unsigned short*)(d.C + off) = f2bf(v);
        }
}

// ---------------------------------------------------------------------------
// Prep: all 7 weight transposes (fp32 KxN -> bf16 NxK) + 3-output time-mix,
// one dispatch. Block (32,8) = 256 threads.
// ---------------------------------------------------------------------------
struct TDesc { const float* in; bf16* out; int K; int N; int tiles; int tx; };
struct PrepArgs {
    TDesc t[7];
    int ttotal;
    const float4 *x, *mk, *mv, *mr;
    ushort4 *ok, *ov, *orr;
};

__global__ __launch_bounds__(256)
void prep_kernel(PrepArgs a)
{
    int blk = blockIdx.x;
    if (blk < a.ttotal) {
        int t = blk, di = 0;
        while (t >= a.t[di].tiles) { t -= a.t[di].tiles; ++di; }
        const float* in  = a.t[di].in;
        bf16*        out = a.t[di].out;
        const int K = a.t[di].K, N = a.t[di].N, tx = a.t[di].tx;
        const int bx = t % tx, by = t / tx;
        __shared__ float tile[32][33];
        const int kt = by * 32, nt = bx * 32;
        #pragma unroll
        for (int i = threadIdx.y; i < 32; i += 8)
            tile[i][threadIdx.x] = in[(size_t)(kt + i) * N + nt + threadIdx.x];
        __syncthreads();
        #pragma unroll
        for (int i = threadIdx.y; i < 32; i += 8)
            out[(size_t)(nt + i) * K + kt + threadIdx.x] =
                __float2bfloat16(tile[threadIdx.x][i]);
    } else {
        const int D4 = DIM / 4;
        int tid = threadIdx.y * 32 + threadIdx.x;
        int e   = (blk - a.ttotal) * 256 + tid;
        int d4  = e & (D4 - 1);
        int t   = (e >> 8) & (TLEN - 1);
        float4 xc = a.x[e];
        float4 sh = make_float4(0.f, 0.f, 0.f, 0.f);
        if (t > 0) sh = a.x[e - D4];
        float4 mk = a.mk[d4], mv = a.mv[d4], mr = a.mr[d4];
        ushort4 u;
        u.x=f2bf(xc.x*mk.x+sh.x*(1.f-mk.x)); u.y=f2bf(xc.y*mk.y+sh.y*(1.f-mk.y));
        u.z=f2bf(xc.z*mk.z+sh.z*(1.f-mk.z)); u.w=f2bf(xc.w*mk.w+sh.w*(1.f-mk.w));
        a.ok[e]=u;
        u.x=f2bf(xc.x*mv.x+sh.x*(1.f-mv.x)); u.y=f2bf(xc.y*mv.y+sh.y*(1.f-mv.y));
        u.z=f2bf(xc.z*mv.z+sh.z*(1.f-mv.z)); u.w=f2bf(xc.w*mv.w+sh.w*(1.f-mv.w));
        a.ov[e]=u;
        u.x=f2bf(xc.x*mr.x+sh.x*(1.f-mr.x)); u.y=f2bf(xc.y*mr.y+sh.y*(1.f-mr.y));
        u.z=f2bf(xc.z*mr.z+sh.z*(1.f-mr.z)); u.w=f2bf(xc.w*mr.w+sh.w*(1.f-mr.w));
        a.orr[e]=u;
    }
}

// fused 2-output token-shift mix (channel mixing)
__global__ __launch_bounds__(256)
void mix2_kernel(const float4* __restrict__ x,
                 const float4* __restrict__ mk, const float4* __restrict__ mr,
                 ushort4* __restrict__ ok, ushort4* __restrict__ orr)
{
    const int D4 = DIM / 4;
    int e   = blockIdx.x * 256 + threadIdx.x;
    int d4  = e & (D4 - 1);
    int t   = (e >> 8) & (TLEN - 1);
    float4 xc = x[e];
    float4 sh = make_float4(0.f, 0.f, 0.f, 0.f);
    if (t > 0) sh = x[e - D4];
    float4 a = mk[d4], c = mr[d4];
    ushort4 u;
    u.x=f2bf(xc.x*a.x+sh.x*(1.f-a.x)); u.y=f2bf(xc.y*a.y+sh.y*(1.f-a.y));
    u.z=f2bf(xc.z*a.z+sh.z*(1.f-a.z)); u.w=f2bf(xc.w*a.w+sh.w*(1.f-a.w));
    ok[e]=u;
    u.x=f2bf(xc.x*c.x+sh.x*(1.f-c.x)); u.y=f2bf(xc.y*c.y+sh.y*(1.f-c.y));
    u.z=f2bf(xc.z*c.z+sh.z*(1.f-c.z)); u.w=f2bf(xc.w*c.w+sh.w*(1.f-c.w));
    orr[e]=u;
}

// WKV scan, chunk-parallel + 64-step discarded warmup (ew <= ~0.5 per channel
// -> carry influence < 1e-19 after warmup). out = r*wkv, may alias R.
#define WKV_CHUNK 64
#define WKV_WARM  64
__global__ __launch_bounds__(256)
void wkv_kernel(const bf16* __restrict__ K, const bf16* __restrict__ V,
                const bf16* __restrict__ R, const float* __restrict__ td,
                bf16* __restrict__ out)
{
    int d     = blockIdx.x * 256 + threadIdx.x;
    int chunk = blockIdx.y;
    int b     = blockIdx.z;
    int start = chunk * WKV_CHUNK;
    int t0    = start - WKV_WARM; if (t0 < 0) t0 = 0;

    float ew = __expf(-__expf(td[d]));
    float num = 0.f, den = 0.f;
    size_t base = ((size_t)b * TLEN) * DIM + d;

    for (int t = t0; t < start; ++t) {
        size_t idx = base + (size_t)t * DIM;
        float ek = __expf(__bfloat162float(K[idx]));
        num = ew * num + ek * __bfloat162float(V[idx]);
        den = ew * den + ek;
    }
    for (int t = start; t < start + WKV_CHUNK; ++t) {
        size_t idx = base + (size_t)t * DIM;
        float ek = __expf(__bfloat162float(K[idx]));
        num = ew * num + ek * __bfloat162float(V[idx]);
        den = ew * den + ek;
        out[idx] = __float2bfloat16(__bfloat162float(R[idx]) * (num / (den + 1e-6f)));
    }
}

extern "C" void kernel_launch(void* const* d_in, const int* in_sizes, int n_in,
                              void* d_out, int out_size, void* d_ws, size_t ws_size,
                              hipStream_t stream)
{
    const float* x   = (const float*)d_in[0];
    const float* td  = (const float*)d_in[1];
    const float* tmk = (const float*)d_in[2];
    const float* tmv = (const float*)d_in[3];
    const float* tmr = (const float*)d_in[4];
    const float* Wk  = (const float*)d_in[5];
    const float* Wv  = (const float*)d_in[6];
    const float* Wr  = (const float*)d_in[7];
    const float* Wo  = (const float*)d_in[8];
    const float* cmk = (const float*)d_in[9];
    const float* cmr = (const float*)d_in[10];
    const float* Wck = (const float*)d_in[11];
    const float* Wcv = (const float*)d_in[12];
    const float* Wcr = (const float*)d_in[13];
    float* out = (float*)d_out;

    // ---- workspace layout: 154 MB peak ----
    // Lifetimes (RACE-CHECKED):
    //  0-26   weights (whole run)
    //  26-58  f0 = x1 fp32 (step 5 -> end)
    //  58-74  bA: xk (2-3) -> xr2 (6-7) -> kh[0:16MB) (8-9)
    //  74-90  bB: xv (2-4) -> kh (8-9)
    //  90-106 bC: xr (2-3) -> kh (8-9)
    //  106-122 bD: k (3-4) -> kh (8-9)
    //  122-138 bE: v (3-4) -> xk2 (6-8)   [kh ends at 122: NO overlap w/ xk2]
    //  138-154 bF: r (3) -> rwkv (4-5) -> r2 (7-9)
    char* ws = (char*)d_ws;
    const size_t MB = 1024 * 1024;
    bf16*  Wk_t  = (bf16*)(ws +   0*MB);
    bf16*  Wv_t  = (bf16*)(ws +   2*MB);
    bf16*  Wr_t  = (bf16*)(ws +   4*MB);
    bf16*  Wo_t  = (bf16*)(ws +   6*MB);
    bf16*  Wcr_t = (bf16*)(ws +   8*MB);
    bf16*  Wck_t = (bf16*)(ws +  10*MB);  // 4096x1024 NxK, 8MB
    bf16*  Wcv_t = (bf16*)(ws +  18*MB);  // 1024x4096 NxK, 8MB
    float* f0    = (float*)(ws + 26*MB);
    bf16*  bA    = (bf16*)(ws +  58*MB);
    bf16*  bB    = (bf16*)(ws +  74*MB);
    bf16*  bC    = (bf16*)(ws +  90*MB);
    bf16*  bD    = (bf16*)(ws + 106*MB);
    bf16*  bE    = (bf16*)(ws + 122*MB);
    bf16*  bF    = (bf16*)(ws + 138*MB);
    bf16*  kh    = bA;                    // 8192x4096 bf16 = 64MB @ 58..122

    const dim3 blk(256);
    const dim3 gblk(512);

    // 1) prep: 7 transposes + time-mix (xk->bA, xv->bB, xr->bC), one dispatch
    {
        PrepArgs pa;
        const float* src[7] = {Wk, Wv, Wr, Wo, Wcr, Wck, Wcv};
        bf16*        dst[7] = {Wk_t, Wv_t, Wr_t, Wo_t, Wcr_t, Wck_t, Wcv_t};
        int          kk[7]  = {DIM, DIM, DIM, DIM, DIM, DIM, HDIM};
        int          nn[7]  = {DIM, DIM, DIM, DIM, DIM, HDIM, DIM};
        int total = 0;
        for (int i = 0; i < 7; ++i) {
            int tx = nn[i] / 32, ty = kk[i] / 32;
            pa.t[i] = {src[i], dst[i], kk[i], nn[i], tx * ty, tx};
            total += tx * ty;
        }
        pa.ttotal = total;
        pa.x  = (const float4*)x;
        pa.mk = (const float4*)tmk; pa.mv = (const float4*)tmv; pa.mr = (const float4*)tmr;
        pa.ok = (ushort4*)bA; pa.ov = (ushort4*)bB; pa.orr = (ushort4*)bC;
        const int mixBlocks = NROWS * DIM / 4 / 256;   // 8192
        prep_kernel<<<dim3(total + mixBlocks), dim3(32, 8), 0, stream>>>(pa);
    }

    // 2) k, v, r GEMMs fused: grid (64, 12) = 768 blocks
    {
        GArgs ga;
        ga.d[0] = {bA, Wk_t, bD, EP_NONE};
        ga.d[1] = {bB, Wv_t, bE, EP_NONE};
        ga.d[2] = {bC, Wr_t, bF, EP_SIGMOID};
        gemm256_multi<<<dim3(NROWS/128, 12), gblk, 0, stream>>>(ga);
    }

    // 3) WKV scan (rwkv = r*wkv, in place over bF)
    dim3 wkvGrid(DIM / 256, TLEN / WKV_CHUNK, BATCH);
    wkv_kernel<<<wkvGrid, blk, 0, stream>>>(bD, bE, bF, td, bF);

    // 4) x1 = x + rwkv @ Wo -> f0 (fp32)   grid 64x4 = 256 blocks
    gemm256<EP_ADD, float><<<dim3(NROWS/128, DIM/256), gblk, 0, stream>>>(
        bF, Wo_t, f0, x, nullptr, DIM, DIM);

    // 5) channel-mix: xk2 -> bE, xr2 -> bA
    mix2_kernel<<<dim3(NROWS * DIM / 4 / 256), blk, 0, stream>>>(
        (const float4*)f0, (const float4*)cmk, (const float4*)cmr,
        (ushort4*)bE, (ushort4*)bA);

    // 6) r2 = sigmoid(xr2 @ Wcr) -> bF  (reads bA BEFORE kh overwrites it)
    gemm256<EP_SIGMOID, bf16><<<dim3(NROWS/128, DIM/256), gblk, 0, stream>>>(
        bA, Wcr_t, bF, nullptr, nullptr, DIM, DIM);

    // 7) kh = sqrelu(xk2 @ Wck) -> 58..122MB   grid 64x16 = 1024 blocks
    gemm256<EP_SQRELU, bf16><<<dim3(NROWS/128, HDIM/256), gblk, 0, stream>>>(
        bE, Wck_t, kh, nullptr, nullptr, HDIM, DIM);

    // 8) out = x1 + r2 * (kh @ Wcv)   grid 64x4, K=4096
    gemm256<EP_FINAL, float><<<dim3(NROWS/128, DIM/256), gblk, 0, stream>>>(
        kh, Wcv_t, out, f0, bF, DIM, HDIM);
}

// Round 9
// 477.786 us; speedup vs baseline: 1.0466x; 1.0466x over previous
//
#include <hip/hip_runtime.h>
#include <hip/hip_bf16.h>
#include <math.h>

// ---------------- problem constants ----------------
#define BATCH 4
#define TLEN  2048
#define DIM   1024
#define NROWS (BATCH*TLEN)      // 8192
#define HDIM  (4*DIM)           // 4096

typedef __hip_bfloat16 bf16;
typedef __attribute__((ext_vector_type(8))) short   shortx8;   // 8 bf16 = 4 VGPR
typedef __attribute__((ext_vector_type(4))) float   floatx4;

__device__ __forceinline__ unsigned short f2bf(float f) {
    bf16 h = __float2bfloat16(f);
    return __builtin_bit_cast(unsigned short, h);
}

__device__ __forceinline__ void async16(const void* g, void* l) {
    // global -> LDS direct DMA, 16B/lane. LDS dest is wave-uniform base + lane*16.
    __builtin_amdgcn_global_load_lds((const __attribute__((address_space(1))) void*)g,
                                     (__attribute__((address_space(3))) void*)l, 16, 0, 0);
}

enum { EP_NONE=0, EP_SIGMOID=1, EP_ADD=2, EP_SQRELU=3, EP_FINAL=4 };

typedef const __attribute__((address_space(3))) char* lds3_t;

// ============================================================================
// R8 post-mortem: per-block staging rate is PINNED at ~14.3 B/cy/CU for the
// 128x256 tile across 5 schedule variants (R2/R4/R5/R8: phase ~1650cy; depth
// 48 vs 72KB in flight: no change).  Remaining lever = staged bytes per FLOP.
// 256^2 tile: 131 F/B vs 87 -> step 7's staged total drops 768 -> 512 MB.
// R6's 256^2 failed at 8 B/cy because its ledger kept only ONE slice (32KB)
// post-wait; every >=14 B/cy structure kept TWO.  gemm_core_big below = 256^2
// tile at the PROVEN depth profile (2 slices / 64KB post-wait, 2-phase cover).
// Used ONLY for step 7 (grid 32x16 = 512 blocks = exactly 2 CU rounds).
// Main core: reverted to the exact R5 5-region code (best measured, 89.7us).
// ============================================================================

// ---------------------------------------------------------------------------
// v5 core (R5 exact): 128x256 tile, 512 thr, 5-region ring, reg frag dbuf,
// asm ds_read + hand lgkm/vm ledger.  Steps 2/4/6/8.
// ---------------------------------------------------------------------------
#define G_REGB   24576       // region bytes (A 8KB + B 16KB)
#define G_ABYTES 8192        // A sub-region bytes
#define G_NSH    (5*12288)   // 5 regions of 12288 shorts = 120 KB

__device__ __forceinline__ void gemm_core(
    const bf16* __restrict__ A, const bf16* __restrict__ Bt, const int K,
    const size_t m0, const size_t n0, short* lds, floatx4 (&acc)[4][4])
{
    const int tid = threadIdx.x;
    char* ldsc = (char*)lds;

    const int rA = tid >> 2;
    const int kA = ((tid & 3) ^ ((rA >> 1) & 3)) << 3;
    const bf16* pA  = A  + (size_t)(m0 + rA) * K + kA;
    const int s1  = 512 + tid;
    const int rB1 = s1 >> 2;
    const int kB1 = ((s1 & 3) ^ ((rB1 >> 1) & 3)) << 3;
    const bf16* pB0 = Bt + (size_t)(n0 + rA)  * K + kA;
    const bf16* pB1 = Bt + (size_t)(n0 + rB1) * K + kB1;
    char* dA  = ldsc + tid * 16;
    char* dB0 = ldsc + G_ABYTES + tid * 16;
    char* dB1 = ldsc + G_ABYTES + 8192 + tid * 16;

    const int lane = tid & 63;
    const int wave = tid >> 6;
    const int wm = (wave >> 2) * 64;
    const int wn = (wave & 3) * 64;
    const int lr = lane & 15, kq = lane >> 4;
    int offA[4], offB[4];
    #pragma unroll
    for (int i = 0; i < 4; ++i) {
        const int ra = wm + i*16 + lr;
        offA[i] = ra*64 + ((kq ^ ((ra>>1)&3)) << 4);
        const int rb = wn + i*16 + lr;
        offB[i] = G_ABYTES + rb*64 + ((kq ^ ((rb>>1)&3)) << 4);
    }

    const int P = K >> 5;

    auto stage = [&](int sl, int reg) {
        const int rB = reg * G_REGB;
        const int ko = sl << 5;
        async16(pA  + ko, dA  + rB);
        async16(pB0 + ko, dB0 + rB);
        async16(pB1 + ko, dB1 + rB);
    };
    auto ldfrag = [&](int reg, shortx8 (&af)[4], shortx8 (&bf_)[4]) {
        const char* rb = ldsc + (size_t)(reg * G_REGB);
        #pragma unroll
        for (int i = 0; i < 4; ++i) {
            lds3_t p = (lds3_t)(rb + offA[i]);
            asm volatile("ds_read_b128 %0, %1" : "=v"(af[i]) : "v"(p));
        }
        #pragma unroll
        for (int i = 0; i < 4; ++i) {
            lds3_t p = (lds3_t)(rb + offB[i]);
            asm volatile("ds_read_b128 %0, %1" : "=v"(bf_[i]) : "v"(p));
        }
    };
    auto domfma = [&](const shortx8 (&af)[4], const shortx8 (&bf_)[4]) {
        __builtin_amdgcn_s_setprio(1);
        #pragma unroll
        for (int mi = 0; mi < 4; ++mi)
            #pragma unroll
            for (int ni = 0; ni < 4; ++ni)
                acc[mi][ni] = __builtin_amdgcn_mfma_f32_16x16x32_bf16(
                                  af[mi], bf_[ni], acc[mi][ni], 0, 0, 0);
        __builtin_amdgcn_s_setprio(0);
    };

    stage(0,0); stage(1,1); stage(2,2); stage(3,3);
    asm volatile("s_waitcnt vmcnt(6)" ::: "memory");
    __builtin_amdgcn_s_barrier();
    __builtin_amdgcn_sched_barrier(0);

    shortx8 fa0[4], fb0[4], fa1[4], fb1[4];
    ldfrag(0, fa0, fb0);

    int cur = 0;
    for (int q = 0; q < P - 4; q += 2) {
        {
            const int sreg = (cur == 0) ? 4 : cur - 1;
            stage(q + 4, sreg);
            const int nxt = (cur == 4) ? 0 : cur + 1;
            ldfrag(nxt, fa1, fb1);
            asm volatile("s_waitcnt lgkmcnt(8)" ::: "memory");
            __builtin_amdgcn_sched_barrier(0);
            domfma(fa0, fb0);
            asm volatile("s_waitcnt vmcnt(6)" ::: "memory");
            __builtin_amdgcn_s_barrier();
            __builtin_amdgcn_sched_barrier(0);
            cur = nxt;
        }
        {
            const int sreg = (cur == 0) ? 4 : cur - 1;
            stage(q + 5, sreg);
            const int nxt = (cur == 4) ? 0 : cur + 1;
            ldfrag(nxt, fa0, fb0);
            asm volatile("s_waitcnt lgkmcnt(8)" ::: "memory");
            __builtin_amdgcn_sched_barrier(0);
            domfma(fa1, fb1);
            asm volatile("s_waitcnt vmcnt(6)" ::: "memory");
            __builtin_amdgcn_s_barrier();
            __builtin_amdgcn_sched_barrier(0);
            cur = nxt;
        }
    }

    {
        const int r1 = (cur == 4) ? 0 : cur + 1;
        ldfrag(r1, fa1, fb1);
        asm volatile("s_waitcnt lgkmcnt(8)" ::: "memory");
        __builtin_amdgcn_sched_barrier(0);
        domfma(fa0, fb0);
        asm volatile("s_waitcnt vmcnt(3)" ::: "memory");
        __builtin_amdgcn_s_barrier();
        __builtin_amdgcn_sched_barrier(0);
        const int r2 = (r1 == 4) ? 0 : r1 + 1;
        ldfrag(r2, fa0, fb0);
        asm volatile("s_waitcnt lgkmcnt(8)" ::: "memory");
        __builtin_amdgcn_sched_barrier(0);
        domfma(fa1, fb1);
        asm volatile("s_waitcnt vmcnt(0)" ::: "memory");
        __builtin_amdgcn_s_barrier();
        __builtin_amdgcn_sched_barrier(0);
        const int r3 = (r2 == 4) ? 0 : r2 + 1;
        ldfrag(r3, fa1, fb1);
        asm volatile("s_waitcnt lgkmcnt(8)" ::: "memory");
        __builtin_amdgcn_sched_barrier(0);
        domfma(fa0, fb0);
        asm volatile("s_waitcnt lgkmcnt(0)" ::: "memory");
        __builtin_amdgcn_sched_barrier(0);
        domfma(fa1, fb1);
    }
}

// epilogue for v5 core: C/D layout col=lane&15, row=(lane>>4)*4+reg
template<int MODE, typename OutT>
__device__ __forceinline__ void epilogue(
    floatx4 (&acc)[4][4], OutT* __restrict__ C,
    const float* __restrict__ addv, const bf16* __restrict__ mulv,
    const size_t m0, const size_t n0, const int N)
{
    const int tid = threadIdx.x;
    const int lane = tid & 63, wave = tid >> 6;
    const size_t r0 = m0 + (size_t)(wave >> 2) * 64 + ((lane >> 4) << 2);
    const size_t c0 = n0 + (size_t)(wave & 3) * 64 + (lane & 15);
    #pragma unroll
    for (int mi = 0; mi < 4; ++mi)
      #pragma unroll
      for (int ni = 0; ni < 4; ++ni)
        #pragma unroll
        for (int r = 0; r < 4; ++r) {
            const size_t off = (r0 + mi*16 + r) * N + c0 + ni*16;
            float v = acc[mi][ni][r];
            if (MODE == EP_SIGMOID)      v = 1.0f / (1.0f + __expf(-v));
            else if (MODE == EP_ADD)     v = addv[off] + v;
            else if (MODE == EP_SQRELU)  { float t = fmaxf(v, 0.0f); v = t * t; }
            else if (MODE == EP_FINAL)   v = addv[off] + __bfloat162float(mulv[off]) * v;
            if (sizeof(OutT) == 2) *(unsigned short*)(C + off) = f2bf(v);
            else                   *(float*)(C + off) = v;
        }
}

template<int MODE, typename OutT>
__global__ __launch_bounds__(512, 2)
void gemm256(const bf16* __restrict__ A, const bf16* __restrict__ Bt,
             OutT* __restrict__ C,
             const float* __restrict__ addv, const bf16* __restrict__ mulv,
             int N, int K)
{
    __shared__ __align__(16) short lds[G_NSH];
    const int nwg  = gridDim.x * gridDim.y;
    const int orig = blockIdx.y * gridDim.x + blockIdx.x;
    const int wg   = (orig & 7) * (nwg >> 3) + (orig >> 3);   // nwg % 8 == 0
    const int bx   = wg % gridDim.x;
    const int by   = wg / gridDim.x;
    const size_t m0 = (size_t)bx * 128;
    const size_t n0 = (size_t)by * 256;
    floatx4 acc[4][4] = {};
    gemm_core(A, Bt, K, m0, n0, lds, acc);
    epilogue<MODE, OutT>(acc, C, addv, mulv, m0, n0, N);
}

// ---------------------------------------------------------------------------
// Multi-GEMM: k/v/r (same M=8192, K=1024, N=1024, bf16 out) in ONE dispatch.
// grid = (64, 12): 4 col tiles per descriptor.
// ---------------------------------------------------------------------------
struct GDesc { const bf16* A; const bf16* Bt; bf16* C; int mode; };
struct GArgs { GDesc d[3]; };

__global__ __launch_bounds__(512, 2)
void gemm256_multi(GArgs args)
{
    __shared__ __align__(16) short lds[G_NSH];
    const int nwg  = gridDim.x * gridDim.y;
    const int orig = blockIdx.y * gridDim.x + blockIdx.x;
    const int wg   = (orig & 7) * (nwg >> 3) + (orig >> 3);
    const int bx   = wg % gridDim.x;
    const int byg  = wg / gridDim.x;         // 0..11
    const int di   = byg >> 2;
    const int by   = byg & 3;
    const GDesc d  = args.d[di];
    const size_t m0 = (size_t)bx * 128;
    const size_t n0 = (size_t)by * 256;
    floatx4 acc[4][4] = {};
    gemm_core(d.A, d.Bt, DIM, m0, n0, lds, acc);

    const int tid = threadIdx.x;
    const int lane = tid & 63, wave = tid >> 6;
    const size_t r0 = m0 + (size_t)(wave >> 2) * 64 + ((lane >> 4) << 2);
    const size_t c0 = n0 + (size_t)(wave & 3) * 64 + (lane & 15);
    const bool sig = (d.mode == EP_SIGMOID);
    #pragma unroll
    for (int mi = 0; mi < 4; ++mi)
      #pragma unroll
      for (int ni = 0; ni < 4; ++ni)
        #pragma unroll
        for (int r = 0; r < 4; ++r) {
            const size_t off = (r0 + mi*16 + r) * DIM + c0 + ni*16;
            float v = acc[mi][ni][r];
            if (sig) v = 1.0f / (1.0f + __expf(-v));
            *(unsigned short*)(d.C + off) = f2bf(v);
        }
}

// ---------------------------------------------------------------------------
// BIG core v2: 256x256 tile, 512 thr (8 waves 2Mx4N), wave tile 128x64.
// Ring of FOUR 32KB regions (A 256x32 + B 256x32) = 128 KB.  Read-current
// schedule (no reg-dbuf: R4/R5 proved that overlap is worth ~0), stage-ahead
// 3, steady vmcnt(8) -> TWO slices (64KB) post-wait, 2-phase cover = the
// proven >=14 B/cy depth profile (R6's 8 B/cy was 1 slice post-wait).
//
// LEDGER (4 loads/stage): prologue stages 0,1,2 (12 loads); vmcnt(8) drains
// slice 0.  Invariant entering phase q: outstanding {q+1,q+2} (8 loads),
// slices <=q landed.  Phase q: stage(q+3) -> {q+1,q+2,q+3}=12; ldfrag(q);
// lgkmcnt(0); 32 MFMA; vmcnt(8) drains q+1 (read next phase); s_barrier.
// Region (q+3)&3's prior occupant = slice q-1: its ds_reads drained by phase
// q-1's lgkmcnt(0) before that phase's MFMA+barrier -> restage safe.
// Tail (no stage): vmcnt(4) drains P-2, vmcnt(0) drains P-1.  Barrier count
// uniform (loop bounds wave-uniform).  Requires P >= 4 (P=32 here).
// Fragment addressing identical to the R6 big core (correctness-verified).
// ---------------------------------------------------------------------------
#define H_REGB   32768       // region bytes: A 16KB + B 16KB
#define H_ABYTES 16384
#define H_NSH    (4*16384)   // 4 regions x 16384 shorts = 128 KB

#define DSR128(dst, p, OFF) \
    asm volatile("ds_read_b128 %0, %1 offset:" OFF : "=v"(dst) : "v"(p))

__device__ __forceinline__ void gemm_core_big(
    const bf16* __restrict__ A, const bf16* __restrict__ Bt, const int K,
    const size_t m0, const size_t n0, short* lds, floatx4 (&acc)[8][4])
{
    const int tid = threadIdx.x;          // 0..511
    char* ldsc = (char*)lds;

    // staging: 4 slots/thread, pre-swizzled global source, linear LDS dest.
    const int rA0 = tid >> 2;             // 0..127
    const int rA1 = 128 + rA0;
    const int kg0 = ((tid & 3) ^ ((rA0 >> 1) & 3)) << 3;
    const int kg1 = ((tid & 3) ^ ((rA1 >> 1) & 3)) << 3;
    const bf16* pA0 = A  + (size_t)(m0 + rA0) * K + kg0;
    const bf16* pA1 = A  + (size_t)(m0 + rA1) * K + kg1;
    const bf16* pB0 = Bt + (size_t)(n0 + rA0) * K + kg0;
    const bf16* pB1 = Bt + (size_t)(n0 + rA1) * K + kg1;
    char* dA0 = ldsc + tid * 16;
    char* dA1 = ldsc + (512 + tid) * 16;
    char* dB0 = ldsc + H_ABYTES + tid * 16;
    char* dB1 = ldsc + H_ABYTES + (512 + tid) * 16;

    // fragment base offsets; offX[i] = offX0 + i*1024 (swizzle XOR term is
    // i-invariant: row step 16 -> (row>>1)&3 unchanged)
    const int lane = tid & 63, wave = tid >> 6;
    const int wm = (wave >> 2) * 128;    // 0 / 128
    const int wn = (wave & 3) * 64;      // 0..192
    const int lr = lane & 15, kq = lane >> 4;
    const int ra0 = wm + lr;
    const int offA0 = ra0 * 64 + ((kq ^ ((ra0 >> 1) & 3)) << 4);
    const int rb0 = wn + lr;
    const int offB0 = H_ABYTES + rb0 * 64 + ((kq ^ ((rb0 >> 1) & 3)) << 4);

    const int P = K >> 5;                // 32 for step 7

    auto stage = [&](int sl, int reg) {
        const int rb = reg * H_REGB;
        const int ko = sl << 5;
        async16(pA0 + ko, dA0 + rb);
        async16(pA1 + ko, dA1 + rb);
        async16(pB0 + ko, dB0 + rb);
        async16(pB1 + ko, dB1 + rb);
    };
    auto ldfrag = [&](int reg, shortx8 (&af)[8], shortx8 (&bf_)[4]) {
        lds3_t pa = (lds3_t)(ldsc + reg * H_REGB + offA0);
        lds3_t pb = (lds3_t)(ldsc + reg * H_REGB + offB0);
        DSR128(af[0], pa, "0");    DSR128(af[1], pa, "1024");
        DSR128(af[2], pa, "2048"); DSR128(af[3], pa, "3072");
        DSR128(af[4], pa, "4096"); DSR128(af[5], pa, "5120");
        DSR128(af[6], pa, "6144"); DSR128(af[7], pa, "7168");
        DSR128(bf_[0], pb, "0");    DSR128(bf_[1], pb, "1024");
        DSR128(bf_[2], pb, "2048"); DSR128(bf_[3], pb, "3072");
    };
    auto domfma = [&](const shortx8 (&af)[8], const shortx8 (&bf_)[4]) {
        __builtin_amdgcn_s_setprio(1);
        #pragma unroll
        for (int mi = 0; mi < 8; ++mi)
            #pragma unroll
            for (int ni = 0; ni < 4; ++ni)
                acc[mi][ni] = __builtin_amdgcn_mfma_f32_16x16x32_bf16(
                                  af[mi], bf_[ni], acc[mi][ni], 0, 0, 0);
        __builtin_amdgcn_s_setprio(0);
    };

    // prologue: stage slices 0,1,2 (12 loads); vmcnt(8) -> slice 0 landed
    stage(0, 0); stage(1, 1); stage(2, 2);
    asm volatile("s_waitcnt vmcnt(8)" ::: "memory");
    __builtin_amdgcn_s_barrier();
    __builtin_amdgcn_sched_barrier(0);

    shortx8 af[8], bf_[4];

    // main phases 0..P-4 (each stages q+3)
    for (int q = 0; q < P - 3; ++q) {
        stage(q + 3, (q + 3) & 3);
        ldfrag(q & 3, af, bf_);
        asm volatile("s_waitcnt lgkmcnt(0)" ::: "memory");
        __builtin_amdgcn_sched_barrier(0);
        domfma(af, bf_);
        asm volatile("s_waitcnt vmcnt(8)" ::: "memory");   // drain slice q+1
        __builtin_amdgcn_s_barrier();
        __builtin_amdgcn_sched_barrier(0);
    }
    // phase P-3: no stage; outstanding {P-2,P-1}=8 -> vmcnt(4) drains P-2
    ldfrag((P - 3) & 3, af, bf_);
    asm volatile("s_waitcnt lgkmcnt(0)" ::: "memory");
    __builtin_amdgcn_sched_barrier(0);
    domfma(af, bf_);
    asm volatile("s_waitcnt vmcnt(4)" ::: "memory");
    __builtin_amdgcn_s_barrier();
    __builtin_amdgcn_sched_barrier(0);
    // phase P-2: outstanding {P-1}=4 -> vmcnt(0)
    ldfrag((P - 2) & 3, af, bf_);
    asm volatile("s_waitcnt lgkmcnt(0)" ::: "memory");
    __builtin_amdgcn_sched_barrier(0);
    domfma(af, bf_);
    asm volatile("s_waitcnt vmcnt(0)" ::: "memory");
    __builtin_amdgcn_s_barrier();
    __builtin_amdgcn_sched_barrier(0);
    // phase P-1
    ldfrag((P - 1) & 3, af, bf_);
    asm volatile("s_waitcnt lgkmcnt(0)" ::: "memory");
    __builtin_amdgcn_sched_barrier(0);
    domfma(af, bf_);
}

// epilogue for big core: wave (2Mx4N), per-wave 128x64 (R6-verified layout)
template<int MODE, typename OutT>
__device__ __forceinline__ void epilogueBig(
    floatx4 (&acc)[8][4], OutT* __restrict__ C,
    const float* __restrict__ addv, const bf16* __restrict__ mulv,
    const size_t m0, const size_t n0, const int N)
{
    const int tid = threadIdx.x;
    const int lane = tid & 63, wave = tid >> 6;
    const size_t r0 = m0 + (size_t)(wave >> 2) * 128 + ((lane >> 4) << 2);
    const size_t c0 = n0 + (size_t)(wave & 3) * 64 + (lane & 15);
    #pragma unroll
    for (int mi = 0; mi < 8; ++mi)
      #pragma unroll
      for (int ni = 0; ni < 4; ++ni)
        #pragma unroll
        for (int r = 0; r < 4; ++r) {
            const size_t off = (r0 + mi*16 + r) * N + c0 + ni*16;
            float v = acc[mi][ni][r];
            if (MODE == EP_SIGMOID)      v = 1.0f / (1.0f + __expf(-v));
            else if (MODE == EP_ADD)     v = addv[off] + v;
            else if (MODE == EP_SQRELU)  { float t = fmaxf(v, 0.0f); v = t * t; }
            else if (MODE == EP_FINAL)   v = addv[off] + __bfloat162float(mulv[off]) * v;
            if (sizeof(OutT) == 2) *(unsigned short*)(C + off) = f2bf(v);
            else                   *(float*)(C + off) = v;
        }
}

template<int MODE, typename OutT>
__global__ __launch_bounds__(512, 2)
void gemmBig(const bf16* __restrict__ A, const bf16* __restrict__ Bt,
             OutT* __restrict__ C,
             const float* __restrict__ addv, const bf16* __restrict__ mulv,
             int N, int K)
{
    __shared__ __align__(16) short lds[H_NSH];
    const int nwg  = gridDim.x * gridDim.y;
    const int orig = blockIdx.y * gridDim.x + blockIdx.x;
    const int wg   = (orig & 7) * (nwg >> 3) + (orig >> 3);   // nwg % 8 == 0
    const int bx   = wg % gridDim.x;
    const int by   = wg / gridDim.x;
    const size_t m0 = (size_t)bx * 256;
    const size_t n0 = (size_t)by * 256;
    floatx4 acc[8][4] = {};
    gemm_core_big(A, Bt, K, m0, n0, lds, acc);
    epilogueBig<MODE, OutT>(acc, C, addv, mulv, m0, n0, N);
}

// ---------------------------------------------------------------------------
// Prep: all 7 weight transposes (fp32 KxN -> bf16 NxK) + 3-output time-mix,
// one dispatch. Block (32,8) = 256 threads.
// ---------------------------------------------------------------------------
struct TDesc { const float* in; bf16* out; int K; int N; int tiles; int tx; };
struct PrepArgs {
    TDesc t[7];
    int ttotal;
    const float4 *x, *mk, *mv, *mr;
    ushort4 *ok, *ov, *orr;
};

__global__ __launch_bounds__(256)
void prep_kernel(PrepArgs a)
{
    int blk = blockIdx.x;
    if (blk < a.ttotal) {
        int t = blk, di = 0;
        while (t >= a.t[di].tiles) { t -= a.t[di].tiles; ++di; }
        const float* in  = a.t[di].in;
        bf16*        out = a.t[di].out;
        const int K = a.t[di].K, N = a.t[di].N, tx = a.t[di].tx;
        const int bx = t % tx, by = t / tx;
        __shared__ float tile[32][33];
        const int kt = by * 32, nt = bx * 32;
        #pragma unroll
        for (int i = threadIdx.y; i < 32; i += 8)
            tile[i][threadIdx.x] = in[(size_t)(kt + i) * N + nt + threadIdx.x];
        __syncthreads();
        #pragma unroll
        for (int i = threadIdx.y; i < 32; i += 8)
            out[(size_t)(nt + i) * K + kt + threadIdx.x] =
                __float2bfloat16(tile[threadIdx.x][i]);
    } else {
        const int D4 = DIM / 4;
        int tid = threadIdx.y * 32 + threadIdx.x;
        int e   = (blk - a.ttotal) * 256 + tid;
        int d4  = e & (D4 - 1);
        int t   = (e >> 8) & (TLEN - 1);
        float4 xc = a.x[e];
        float4 sh = make_float4(0.f, 0.f, 0.f, 0.f);
        if (t > 0) sh = a.x[e - D4];
        float4 mk = a.mk[d4], mv = a.mv[d4], mr = a.mr[d4];
        ushort4 u;
        u.x=f2bf(xc.x*mk.x+sh.x*(1.f-mk.x)); u.y=f2bf(xc.y*mk.y+sh.y*(1.f-mk.y));
        u.z=f2bf(xc.z*mk.z+sh.z*(1.f-mk.z)); u.w=f2bf(xc.w*mk.w+sh.w*(1.f-mk.w));
        a.ok[e]=u;
        u.x=f2bf(xc.x*mv.x+sh.x*(1.f-mv.x)); u.y=f2bf(xc.y*mv.y+sh.y*(1.f-mv.y));
        u.z=f2bf(xc.z*mv.z+sh.z*(1.f-mv.z)); u.w=f2bf(xc.w*mv.w+sh.w*(1.f-mv.w));
        a.ov[e]=u;
        u.x=f2bf(xc.x*mr.x+sh.x*(1.f-mr.x)); u.y=f2bf(xc.y*mr.y+sh.y*(1.f-mr.y));
        u.z=f2bf(xc.z*mr.z+sh.z*(1.f-mr.z)); u.w=f2bf(xc.w*mr.w+sh.w*(1.f-mr.w));
        a.orr[e]=u;
    }
}

// fused 2-output token-shift mix (channel mixing)
__global__ __launch_bounds__(256)
void mix2_kernel(const float4* __restrict__ x,
                 const float4* __restrict__ mk, const float4* __restrict__ mr,
                 ushort4* __restrict__ ok, ushort4* __restrict__ orr)
{
    const int D4 = DIM / 4;
    int e   = blockIdx.x * 256 + threadIdx.x;
    int d4  = e & (D4 - 1);
    int t   = (e >> 8) & (TLEN - 1);
    float4 xc = x[e];
    float4 sh = make_float4(0.f, 0.f, 0.f, 0.f);
    if (t > 0) sh = x[e - D4];
    float4 a = mk[d4], c = mr[d4];
    ushort4 u;
    u.x=f2bf(xc.x*a.x+sh.x*(1.f-a.x)); u.y=f2bf(xc.y*a.y+sh.y*(1.f-a.y));
    u.z=f2bf(xc.z*a.z+sh.z*(1.f-a.z)); u.w=f2bf(xc.w*a.w+sh.w*(1.f-a.w));
    ok[e]=u;
    u.x=f2bf(xc.x*c.x+sh.x*(1.f-c.x)); u.y=f2bf(xc.y*c.y+sh.y*(1.f-c.y));
    u.z=f2bf(xc.z*c.z+sh.z*(1.f-c.z)); u.w=f2bf(xc.w*c.w+sh.w*(1.f-c.w));
    orr[e]=u;
}

// WKV scan, chunk-parallel + 64-step discarded warmup (ew <= ~0.5 per channel
// -> carry influence < 1e-19 after warmup). out = r*wkv, may alias R.
#define WKV_CHUNK 64
#define WKV_WARM  64
__global__ __launch_bounds__(256)
void wkv_kernel(const bf16* __restrict__ K, const bf16* __restrict__ V,
                const bf16* __restrict__ R, const float* __restrict__ td,
                bf16* __restrict__ out)
{
    int d     = blockIdx.x * 256 + threadIdx.x;
    int chunk = blockIdx.y;
    int b     = blockIdx.z;
    int start = chunk * WKV_CHUNK;
    int t0    = start - WKV_WARM; if (t0 < 0) t0 = 0;

    float ew = __expf(-__expf(td[d]));
    float num = 0.f, den = 0.f;
    size_t base = ((size_t)b * TLEN) * DIM + d;

    for (int t = t0; t < start; ++t) {
        size_t idx = base + (size_t)t * DIM;
        float ek = __expf(__bfloat162float(K[idx]));
        num = ew * num + ek * __bfloat162float(V[idx]);
        den = ew * den + ek;
    }
    for (int t = start; t < start + WKV_CHUNK; ++t) {
        size_t idx = base + (size_t)t * DIM;
        float ek = __expf(__bfloat162float(K[idx]));
        num = ew * num + ek * __bfloat162float(V[idx]);
        den = ew * den + ek;
        out[idx] = __float2bfloat16(__bfloat162float(R[idx]) * (num / (den + 1e-6f)));
    }
}

extern "C" void kernel_launch(void* const* d_in, const int* in_sizes, int n_in,
                              void* d_out, int out_size, void* d_ws, size_t ws_size,
                              hipStream_t stream)
{
    const float* x   = (const float*)d_in[0];
    const float* td  = (const float*)d_in[1];
    const float* tmk = (const float*)d_in[2];
    const float* tmv = (const float*)d_in[3];
    const float* tmr = (const float*)d_in[4];
    const float* Wk  = (const float*)d_in[5];
    const float* Wv  = (const float*)d_in[6];
    const float* Wr  = (const float*)d_in[7];
    const float* Wo  = (const float*)d_in[8];
    const float* cmk = (const float*)d_in[9];
    const float* cmr = (const float*)d_in[10];
    const float* Wck = (const float*)d_in[11];
    const float* Wcv = (const float*)d_in[12];
    const float* Wcr = (const float*)d_in[13];
    float* out = (float*)d_out;

    // ---- workspace layout: 154 MB peak ----
    // Lifetimes (RACE-CHECKED):
    //  0-26   weights (whole run)
    //  26-58  f0 = x1 fp32 (step 5 -> end)
    //  58-74  bA: xk (2-3) -> xr2 (6-7) -> kh[0:16MB) (8-9)
    //  74-90  bB: xv (2-4) -> kh (8-9)
    //  90-106 bC: xr (2-3) -> kh (8-9)
    //  106-122 bD: k (3-4) -> kh (8-9)
    //  122-138 bE: v (3-4) -> xk2 (6-8)   [kh ends at 122: NO overlap w/ xk2]
    //  138-154 bF: r (3) -> rwkv (4-5) -> r2 (7-9)
    char* ws = (char*)d_ws;
    const size_t MB = 1024 * 1024;
    bf16*  Wk_t  = (bf16*)(ws +   0*MB);
    bf16*  Wv_t  = (bf16*)(ws +   2*MB);
    bf16*  Wr_t  = (bf16*)(ws +   4*MB);
    bf16*  Wo_t  = (bf16*)(ws +   6*MB);
    bf16*  Wcr_t = (bf16*)(ws +   8*MB);
    bf16*  Wck_t = (bf16*)(ws +  10*MB);  // 4096x1024 NxK, 8MB
    bf16*  Wcv_t = (bf16*)(ws +  18*MB);  // 1024x4096 NxK, 8MB
    float* f0    = (float*)(ws + 26*MB);
    bf16*  bA    = (bf16*)(ws +  58*MB);
    bf16*  bB    = (bf16*)(ws +  74*MB);
    bf16*  bC    = (bf16*)(ws +  90*MB);
    bf16*  bD    = (bf16*)(ws + 106*MB);
    bf16*  bE    = (bf16*)(ws + 122*MB);
    bf16*  bF    = (bf16*)(ws + 138*MB);
    bf16*  kh    = bA;                    // 8192x4096 bf16 = 64MB @ 58..122

    const dim3 blk(256);
    const dim3 gblk(512);

    // 1) prep: 7 transposes + time-mix (xk->bA, xv->bB, xr->bC), one dispatch
    {
        PrepArgs pa;
        const float* src[7] = {Wk, Wv, Wr, Wo, Wcr, Wck, Wcv};
        bf16*        dst[7] = {Wk_t, Wv_t, Wr_t, Wo_t, Wcr_t, Wck_t, Wcv_t};
        int          kk[7]  = {DIM, DIM, DIM, DIM, DIM, DIM, HDIM};
        int          nn[7]  = {DIM, DIM, DIM, DIM, DIM, HDIM, DIM};
        int total = 0;
        for (int i = 0; i < 7; ++i) {
            int tx = nn[i] / 32, ty = kk[i] / 32;
            pa.t[i] = {src[i], dst[i], kk[i], nn[i], tx * ty, tx};
            total += tx * ty;
        }
        pa.ttotal = total;
        pa.x  = (const float4*)x;
        pa.mk = (const float4*)tmk; pa.mv = (const float4*)tmv; pa.mr = (const float4*)tmr;
        pa.ok = (ushort4*)bA; pa.ov = (ushort4*)bB; pa.orr = (ushort4*)bC;
        const int mixBlocks = NROWS * DIM / 4 / 256;   // 8192
        prep_kernel<<<dim3(total + mixBlocks), dim3(32, 8), 0, stream>>>(pa);
    }

    // 2) k, v, r GEMMs fused: grid (64, 12) = 768 blocks
    {
        GArgs ga;
        ga.d[0] = {bA, Wk_t, bD, EP_NONE};
        ga.d[1] = {bB, Wv_t, bE, EP_NONE};
        ga.d[2] = {bC, Wr_t, bF, EP_SIGMOID};
        gemm256_multi<<<dim3(NROWS/128, 12), gblk, 0, stream>>>(ga);
    }

    // 3) WKV scan (rwkv = r*wkv, in place over bF)
    dim3 wkvGrid(DIM / 256, TLEN / WKV_CHUNK, BATCH);
    wkv_kernel<<<wkvGrid, blk, 0, stream>>>(bD, bE, bF, td, bF);

    // 4) x1 = x + rwkv @ Wo -> f0 (fp32)   grid 64x4 = 256 blocks
    gemm256<EP_ADD, float><<<dim3(NROWS/128, DIM/256), gblk, 0, stream>>>(
        bF, Wo_t, f0, x, nullptr, DIM, DIM);

    // 5) channel-mix: xk2 -> bE, xr2 -> bA
    mix2_kernel<<<dim3(NROWS * DIM / 4 / 256), blk, 0, stream>>>(
        (const float4*)f0, (const float4*)cmk, (const float4*)cmr,
        (ushort4*)bE, (ushort4*)bA);

    // 6) r2 = sigmoid(xr2 @ Wcr) -> bF  (reads bA BEFORE kh overwrites it)
    gemm256<EP_SIGMOID, bf16><<<dim3(NROWS/128, DIM/256), gblk, 0, stream>>>(
        bA, Wcr_t, bF, nullptr, nullptr, DIM, DIM);

    // 7) kh = sqrelu(xk2 @ Wck) on 256^2 core: grid (32,16) = 512 blocks
    gemmBig<EP_SQRELU, bf16><<<dim3(NROWS/256, HDIM/256), gblk, 0, stream>>>(
        bE, Wck_t, kh, nullptr, nullptr, HDIM, DIM);

    // 8) out = x1 + r2 * (kh @ Wcv)   grid 64x4, K=4096
    gemm256<EP_FINAL, float><<<dim3(NROWS/128, DIM/256), gblk, 0, stream>>>(
        kh, Wcv_t, out, f0, bF, DIM, HDIM);
}